// Round 8
// baseline (786.795 us; speedup 1.0000x reference)
//
#include <hip/hip_runtime.h>
#include <stdint.h>

#define NN 50000
#define NE 500000
#define BLK 256
#define NEB ((NE + 63) / 64)
#define SST 136   // LDS row stride in shorts (272 B)

#define BARRIER() asm volatile("s_waitcnt lgkmcnt(0)\n\ts_barrier" ::: "memory")

typedef __attribute__((ext_vector_type(8))) short bf16x8;
typedef __attribute__((ext_vector_type(4))) float f32x4;

__device__ __forceinline__ float silu(float x) { return x / (1.0f + __expf(-x)); }
__device__ __forceinline__ float bf2f(unsigned short s) {
    union { unsigned int u; float f; } v; v.u = ((unsigned int)s) << 16; return v.f;
}
__device__ __forceinline__ unsigned short f2bf(float f) {   // RNE
    union { float f; unsigned int u; } v; v.f = f;
    return (unsigned short)((v.u + 0x7fffu + ((v.u >> 16) & 1u)) >> 16);
}
__device__ __forceinline__ unsigned int pack2(float a, float b) {
    return (unsigned int)f2bf(a) | ((unsigned int)f2bf(b) << 16);
}
__device__ __forceinline__ bf16x8 packf8(const float* p) {
    float4 f0 = *(const float4*)p; float4 f1 = *(const float4*)(p + 4);
    union { bf16x8 v; unsigned int u[4]; } o;
    o.u[0] = pack2(f0.x, f0.y); o.u[1] = pack2(f0.z, f0.w);
    o.u[2] = pack2(f1.x, f1.y); o.u[3] = pack2(f1.z, f1.w);
    return o.v;
}

// ---------------- fused setup: prep_h | prep_w | csr_count by block range ----------------
__global__ void setup_all(const float* __restrict__ h, unsigned short* __restrict__ hb,
                          const float* __restrict__ We1, const float* __restrict__ We2,
                          const float* __restrict__ Wc1, const float* __restrict__ Wv1,
                          const float* __restrict__ Wn1, const float* __restrict__ Wn2,
                          unsigned short* __restrict__ Wt1, unsigned short* __restrict__ Wt2,
                          unsigned short* __restrict__ Wt3, unsigned short* __restrict__ Wv1t,
                          unsigned short* __restrict__ Wn1t, unsigned short* __restrict__ Wn2t,
                          const int* __restrict__ eidx, int* __restrict__ deg) {
    int bid = blockIdx.x;
    if (bid < 6250) {                       // prep_h: fp32 -> bf16
        int i = bid * 256 + threadIdx.x;
        if (i < NN * 128 / 4) {
            float4 v = ((const float4*)h)[i];
            uint2 o; o.x = pack2(v.x, v.y); o.y = pack2(v.z, v.w);
            ((uint2*)hb)[i] = o;
        }
    } else if (bid < 6762) {                // prep_w: B^T layouts (sigma: orig_k = (ks%8)*16+ks/8)
        int i = (bid - 6250) * 256 + threadIdx.x;
        if (i < 32768) {                                    // Wt1 [128][256] natural
            int j = i >> 8, k = i & 255;
            Wt1[i] = f2bf(We1[k * 128 + j]);
        } else if (i < 49152) {                             // Wt2 sigma
            int t = i - 32768; int j = t >> 7, ks = t & 127;
            int k0 = (ks & 7) * 16 + (ks >> 3);
            Wt2[t] = f2bf(We2[k0 * 128 + j]);
        } else if (i < 65536) {                             // Wt3 sigma
            int t = i - 49152; int j = t >> 7, ks = t & 127;
            int k0 = (ks & 7) * 16 + (ks >> 3);
            Wt3[t] = f2bf(Wc1[k0 * 128 + j]);
        } else if (i < 81920) {                             // Wv1t natural
            int t = i - 65536; int j = t >> 7, k = t & 127;
            Wv1t[t] = f2bf(Wv1[k * 128 + j]);
        } else if (i < 114688) {                            // Wn1t: h natural, m sigma
            int t = i - 81920; int j = t >> 8, k = t & 255;
            int ksrc;
            if (k < 128) ksrc = k;
            else { int ks = k - 128; ksrc = 128 + (ks & 7) * 16 + (ks >> 3); }
            Wn1t[t] = f2bf(Wn1[ksrc * 128 + j]);
        } else if (i < 131072) {                            // Wn2t sigma
            int t = i - 114688; int j = t >> 7, ks = t & 127;
            int k0 = (ks & 7) * 16 + (ks >> 3);
            Wn2t[t] = f2bf(Wn2[k0 * 128 + j]);
        }
    } else {                                // csr_count
        int e = (bid - 6762) * 256 + threadIdx.x;
        if (e < NE) atomicAdd(&deg[eidx[e]], 1);
    }
}

// ---------------- single-kernel scan: block-local excl scan + atomic base ----------------
// Monotonic global order is NOT needed: segmented reduction only needs same-r contiguity.
__global__ void scan_fused(const int* __restrict__ deg, int* __restrict__ gcount,
                           int* __restrict__ rowptr) {
    __shared__ int s[256];
    __shared__ int base;
    int t = threadIdx.x, idx = blockIdx.x * 256 + t;
    int v = (idx < NN) ? deg[idx] : 0;
    s[t] = v;
    __syncthreads();
    for (int off = 1; off < 256; off <<= 1) {
        int x = (t >= off) ? s[t - off] : 0;
        __syncthreads();
        s[t] += x;
        __syncthreads();
    }
    if (t == 255) base = atomicAdd(gcount, s[255]);
    __syncthreads();
    if (idx < NN) rowptr[idx] = base + s[t] - v;
}

__global__ void csr_fill(const int* __restrict__ eidx, const int* __restrict__ rowptr,
                         int* __restrict__ cursor,
                         int* __restrict__ csr_r, int* __restrict__ csr_c) {
    int e = blockIdx.x * 256 + threadIdx.x;
    if (e < NE) {
        int r = eidx[e], c = eidx[NE + e];
        int slot = rowptr[r] + atomicAdd(&cursor[r], 1);
        csr_r[slot] = r; csr_c[slot] = c;
    }
}

// ---------------- edge kernel: 64-edge tiles, B direct, no spills ----------------
__global__ __launch_bounds__(BLK, 4) void egcl_edge(
    const float* __restrict__ coord,
    const int* __restrict__ csr_r, const int* __restrict__ csr_c,
    const unsigned short* __restrict__ hb,
    const unsigned short* __restrict__ Wt1,
    const unsigned short* __restrict__ Wt2,
    const unsigned short* __restrict__ Wt3,
    const float* __restrict__ We1,
    const float* __restrict__ be1, const float* __restrict__ be2,
    const float* __restrict__ bc1,
    const float* __restrict__ Wc2, const float* __restrict__ bc2,
    float* __restrict__ m_acc, float* __restrict__ c_sum)
{
    __shared__ __align__(16) unsigned short sAb[64 * SST];   // 17408 B
    __shared__ float sRad[64], sDif[64][3];
    __shared__ int sSeg[64];
    __shared__ float sBe1[128], sBe2[128], sBc1[128], sWlast[128], sWc2f[128];

    const int tid = threadIdx.x;
    const int wv = tid >> 6, lane = tid & 63, q = lane >> 4, l16 = lane & 15;
    const int e0 = blockIdx.x * 64;

    if (tid < 128) {
        sBe1[tid] = be1[tid]; sBe2[tid] = be2[tid]; sBc1[tid] = bc1[tid];
        sWlast[tid] = We1[256 * 128 + tid]; sWc2f[tid] = Wc2[tid];
    }
    if (tid < 64) {
        int s = e0 + tid; int sc = (s < NE) ? s : (NE - 1);
        int r = csr_r[sc], c = csr_c[sc];
        sSeg[tid] = (s < NE) ? r : -1;
        float dx = coord[r * 3 + 0] - coord[c * 3 + 0];
        float dy = coord[r * 3 + 1] - coord[c * 3 + 1];
        float dz = coord[r * 3 + 2] - coord[c * 3 + 2];
        float rad = fmaf(dx, dx, fmaf(dy, dy, dz * dz));
        float inv = 1.0f / (sqrtf(rad) + 1e-8f);
        sRad[tid] = rad;
        sDif[tid][0] = dx * inv; sDif[tid][1] = dy * inv; sDif[tid][2] = dz * inv;
    }
    const float bc2v = bc2[0];

    f32x4 acc[8];
#pragma unroll
    for (int ct = 0; ct < 8; ++ct) acc[ct] = (f32x4){0.f, 0.f, 0.f, 0.f};

    // ---- e1 K-half 0: A = h[r]
    {
        int e = e0 + wv * 16 + l16; if (e >= NE) e = NE - 1;
        int nr = csr_r[e];
        bf16x8 a[4];
#pragma unroll
        for (int kc = 0; kc < 4; ++kc)
            a[kc] = *(const bf16x8*)(hb + (size_t)nr * 128 + kc * 32 + q * 8);
#pragma unroll
        for (int kc = 0; kc < 4; ++kc)
#pragma unroll
            for (int ct = 0; ct < 8; ++ct) {
                bf16x8 b = *(const bf16x8*)(Wt1 + (size_t)(ct * 16 + l16) * 256 + kc * 32 + q * 8);
                acc[ct] = __builtin_amdgcn_mfma_f32_16x16x32_bf16(a[kc], b, acc[ct], 0, 0, 0);
            }
    }
    // ---- e1 K-half 1: A = h[c]
    {
        int e = e0 + wv * 16 + l16; if (e >= NE) e = NE - 1;
        int nc = csr_c[e];
        bf16x8 a[4];
#pragma unroll
        for (int kc = 0; kc < 4; ++kc)
            a[kc] = *(const bf16x8*)(hb + (size_t)nc * 128 + kc * 32 + q * 8);
#pragma unroll
        for (int kc = 0; kc < 4; ++kc)
#pragma unroll
            for (int ct = 0; ct < 8; ++ct) {
                bf16x8 b = *(const bf16x8*)(Wt1 + (size_t)(ct * 16 + l16) * 256 + 128 + kc * 32 + q * 8);
                acc[ct] = __builtin_amdgcn_mfma_f32_16x16x32_bf16(a[kc], b, acc[ct], 0, 0, 0);
            }
    }

    BARRIER();   // A: geometry visible

    // e1 epilogue: t1 = silu(acc + rad*Wlast + be1) -> sigma pack into sAb
#pragma unroll
    for (int r = 0; r < 4; ++r) {
        int row = wv * 16 + q * 4 + r;
        float rad = sRad[row];
        float v[8];
#pragma unroll
        for (int ct = 0; ct < 8; ++ct) {
            int col = ct * 16 + l16;
            v[ct] = silu(acc[ct][r] + rad * sWlast[col] + sBe1[col]);
        }
        uint4 pk = make_uint4(pack2(v[0], v[1]), pack2(v[2], v[3]),
                              pack2(v[4], v[5]), pack2(v[6], v[7]));
        *(uint4*)(sAb + row * SST + l16 * 8) = pk;
    }

    BARRIER();   // B: t1 visible

    // ---- e2: A from sAb, B from global Wt2 (sigma)
#pragma unroll
    for (int ct = 0; ct < 8; ++ct) acc[ct] = (f32x4){0.f, 0.f, 0.f, 0.f};
    {
        bf16x8 a[4];
        int row = wv * 16 + l16;
#pragma unroll
        for (int kc = 0; kc < 4; ++kc)
            a[kc] = *(const bf16x8*)(sAb + row * SST + kc * 32 + q * 8);
#pragma unroll
        for (int kc = 0; kc < 4; ++kc)
#pragma unroll
            for (int ct = 0; ct < 8; ++ct) {
                bf16x8 b = *(const bf16x8*)(Wt2 + (size_t)(ct * 16 + l16) * 128 + kc * 32 + q * 8);
                acc[ct] = __builtin_amdgcn_mfma_f32_16x16x32_bf16(a[kc], b, acc[ct], 0, 0, 0);
            }
    }
    uint4 mu[4];
#pragma unroll
    for (int r = 0; r < 4; ++r) {
        float v[8];
#pragma unroll
        for (int ct = 0; ct < 8; ++ct) v[ct] = silu(acc[ct][r] + sBe2[ct * 16 + l16]);
        mu[r] = make_uint4(pack2(v[0], v[1]), pack2(v[2], v[3]),
                           pack2(v[4], v[5]), pack2(v[6], v[7]));
    }
    BARRIER();   // C: e2 A-reads done
#pragma unroll
    for (int r = 0; r < 4; ++r) {
        int row = wv * 16 + q * 4 + r;
        *(uint4*)(sAb + row * SST + l16 * 8) = mu[r];
    }
    BARRIER();   // D: m visible

    // ---- c1: A from sAb, B from global Wt3 (sigma)
#pragma unroll
    for (int ct = 0; ct < 8; ++ct) acc[ct] = (f32x4){0.f, 0.f, 0.f, 0.f};
    {
        bf16x8 a[4];
        int row = wv * 16 + l16;
#pragma unroll
        for (int kc = 0; kc < 4; ++kc)
            a[kc] = *(const bf16x8*)(sAb + row * SST + kc * 32 + q * 8);
#pragma unroll
        for (int kc = 0; kc < 4; ++kc)
#pragma unroll
            for (int ct = 0; ct < 8; ++ct) {
                bf16x8 b = *(const bf16x8*)(Wt3 + (size_t)(ct * 16 + l16) * 128 + kc * 32 + q * 8);
                acc[ct] = __builtin_amdgcn_mfma_f32_16x16x32_bf16(a[kc], b, acc[ct], 0, 0, 0);
            }
    }
    // c2: silu -> dot Wc2 -> 16-lane reduce -> c_sum atomics
    {
        float p[4];
#pragma unroll
        for (int r = 0; r < 4; ++r) {
            float s = 0.f;
#pragma unroll
            for (int ct = 0; ct < 8; ++ct) {
                int col = ct * 16 + l16;
                float t = silu(acc[ct][r] + sBc1[col]);
                s = fmaf(t, sWc2f[col], s);
            }
            p[r] = s;
        }
#pragma unroll
        for (int m = 1; m < 16; m <<= 1)
#pragma unroll
            for (int r = 0; r < 4; ++r) p[r] += __shfl_xor(p[r], m, 16);
        if (l16 == 0) {
#pragma unroll
            for (int r = 0; r < 4; ++r) {
                int row = wv * 16 + q * 4 + r;
                int rn = sSeg[row];
                if (rn >= 0) {
                    float w = p[r] + bc2v;
                    atomicAdd(&c_sum[(size_t)rn * 3 + 0], sDif[row][0] * w);
                    atomicAdd(&c_sum[(size_t)rn * 3 + 1], sDif[row][1] * w);
                    atomicAdd(&c_sum[(size_t)rn * 3 + 2], sDif[row][2] * w);
                }
            }
        }
    }

    // ---- segmented m reduction: element p over rows [half*32, half*32+32)
    {
        int p = tid & 127, half = tid >> 7;
        int base = half * 32;
        float run = 0.f;
        int cur = sSeg[base];
        bool openL = true;
#pragma unroll 1
        for (int i = 0; i < 32; ++i) {
            int row = base + i;
            int rr = sSeg[row];
            if (rr != cur) {
                if (cur >= 0) {
                    float* dst = &m_acc[(size_t)cur * 128 + p];
                    if (openL) atomicAdd(dst, run);
                    else       *dst = run;   // window-interior run: exclusive writer
                }
                run = 0.f; cur = rr; openL = false;
            }
            run += bf2f(sAb[row * SST + p]);
        }
        if (cur >= 0) atomicAdd(&m_acc[(size_t)cur * 128 + p], run);
    }
}

// ---------------- node kernel: 64 nodes/block ----------------
__global__ __launch_bounds__(BLK, 4) void egcl_node(
    const unsigned short* __restrict__ hb,
    const float* __restrict__ coord,
    const float* __restrict__ vel,
    const unsigned short* __restrict__ Wv1t, const float* __restrict__ bv1,
    const float* __restrict__ Wv2, const float* __restrict__ bv2,
    const unsigned short* __restrict__ Wn1t, const float* __restrict__ bn1,
    const unsigned short* __restrict__ Wn2t, const float* __restrict__ bn2,
    const float* __restrict__ m_acc, const float* __restrict__ c_sum,
    float* __restrict__ out_h, float* __restrict__ out_c)
{
    __shared__ __align__(16) unsigned short sAb[64 * SST];
    __shared__ float sBv1[128], sWv2f[128], sBn1[128], sBn2[128];

    const int tid = threadIdx.x;
    const int wv = tid >> 6, lane = tid & 63, q = lane >> 4, l16 = lane & 15;
    const int n0 = blockIdx.x * 64;
    int nval = NN - n0; if (nval > 64) nval = 64;

    if (tid < 128) {
        sBv1[tid] = bv1[tid]; sWv2f[tid] = Wv2[tid];
        sBn1[tid] = bn1[tid]; sBn2[tid] = bn2[tid];
    }
    const float bv2v = bv2[0];

    bf16x8 ah[4], am[4];
    {
        int row = wv * 16 + l16;
        int nn = n0 + row; if (nn >= NN) nn = NN - 1;
#pragma unroll
        for (int kc = 0; kc < 4; ++kc) {
            ah[kc] = *(const bf16x8*)(hb + (size_t)nn * 128 + kc * 32 + q * 8);
            am[kc] = packf8(m_acc + (size_t)nn * 128 + kc * 32 + q * 8);
        }
    }

    BARRIER();   // biases visible

    f32x4 acc[8];
    // ---- vel MLP
#pragma unroll
    for (int ct = 0; ct < 8; ++ct) acc[ct] = (f32x4){0.f, 0.f, 0.f, 0.f};
#pragma unroll
    for (int kc = 0; kc < 4; ++kc)
#pragma unroll
        for (int ct = 0; ct < 8; ++ct) {
            bf16x8 b = *(const bf16x8*)(Wv1t + (size_t)(ct * 16 + l16) * 128 + kc * 32 + q * 8);
            acc[ct] = __builtin_amdgcn_mfma_f32_16x16x32_bf16(ah[kc], b, acc[ct], 0, 0, 0);
        }
    {
        float p[4];
#pragma unroll
        for (int r = 0; r < 4; ++r) {
            float s = 0.f;
#pragma unroll
            for (int ct = 0; ct < 8; ++ct) {
                int col = ct * 16 + l16;
                float t = silu(acc[ct][r] + sBv1[col]);
                s = fmaf(t, sWv2f[col], s);
            }
            p[r] = s;
        }
#pragma unroll
        for (int m = 1; m < 16; m <<= 1)
#pragma unroll
            for (int r = 0; r < 4; ++r) p[r] += __shfl_xor(p[r], m, 16);
        if (l16 == 0) {
#pragma unroll
            for (int r = 0; r < 4; ++r) {
                int row = wv * 16 + q * 4 + r;
                int n = n0 + row;
                if (row < nval) {
                    float vw = p[r] + bv2v;
#pragma unroll
                    for (int d = 0; d < 3; ++d) {
                        float cv = coord[(size_t)n * 3 + d] + c_sum[(size_t)n * 3 + d]
                                 + vel[(size_t)n * 3 + d] * vw;
                        out_c[(size_t)n * 3 + d] = cv;
                    }
                }
            }
        }
    }

    // ---- n1: K=256 on [h | m_i]
#pragma unroll
    for (int ct = 0; ct < 8; ++ct) acc[ct] = (f32x4){0.f, 0.f, 0.f, 0.f};
#pragma unroll
    for (int kc = 0; kc < 8; ++kc)
#pragma unroll
        for (int ct = 0; ct < 8; ++ct) {
            bf16x8 b = *(const bf16x8*)(Wn1t + (size_t)(ct * 16 + l16) * 256 + kc * 32 + q * 8);
            bf16x8 a = (kc < 4) ? ah[kc & 3] : am[kc & 3];
            acc[ct] = __builtin_amdgcn_mfma_f32_16x16x32_bf16(a, b, acc[ct], 0, 0, 0);
        }
#pragma unroll
    for (int r = 0; r < 4; ++r) {
        int row = wv * 16 + q * 4 + r;
        float v[8];
#pragma unroll
        for (int ct = 0; ct < 8; ++ct) v[ct] = silu(acc[ct][r] + sBn1[ct * 16 + l16]);
        uint4 pk = make_uint4(pack2(v[0], v[1]), pack2(v[2], v[3]),
                              pack2(v[4], v[5]), pack2(v[6], v[7]));
        *(uint4*)(sAb + row * SST + l16 * 8) = pk;
    }

    BARRIER();   // t1 visible

    // ---- n2
#pragma unroll
    for (int ct = 0; ct < 8; ++ct) acc[ct] = (f32x4){0.f, 0.f, 0.f, 0.f};
    {
        bf16x8 a[4];
        int row = wv * 16 + l16;
#pragma unroll
        for (int kc = 0; kc < 4; ++kc)
            a[kc] = *(const bf16x8*)(sAb + row * SST + kc * 32 + q * 8);
#pragma unroll
        for (int kc = 0; kc < 4; ++kc)
#pragma unroll
            for (int ct = 0; ct < 8; ++ct) {
                bf16x8 b = *(const bf16x8*)(Wn2t + (size_t)(ct * 16 + l16) * 128 + kc * 32 + q * 8);
                acc[ct] = __builtin_amdgcn_mfma_f32_16x16x32_bf16(a[kc], b, acc[ct], 0, 0, 0);
            }
    }
#pragma unroll
    for (int r = 0; r < 4; ++r) {
        int row = wv * 16 + q * 4 + r;
        if (row < nval) {
            float* orow = out_h + (size_t)(n0 + row) * 128;
#pragma unroll
            for (int ct = 0; ct < 8; ++ct)
                orow[ct * 16 + l16] = acc[ct][r] + sBn2[ct * 16 + l16];
        }
    }
}

extern "C" void kernel_launch(void* const* d_in, const int* in_sizes, int n_in,
                              void* d_out, int out_size, void* d_ws, size_t ws_size,
                              hipStream_t stream) {
    const float* h     = (const float*)d_in[0];
    const float* coord = (const float*)d_in[1];
    const float* vel   = (const float*)d_in[2];
    const int*   eidx  = (const int*)d_in[3];
    const float* We1 = (const float*)d_in[4];
    const float* be1 = (const float*)d_in[5];
    const float* We2 = (const float*)d_in[6];
    const float* be2 = (const float*)d_in[7];
    const float* Wc1 = (const float*)d_in[8];
    const float* bc1 = (const float*)d_in[9];
    const float* Wc2 = (const float*)d_in[10];
    const float* bc2 = (const float*)d_in[11];
    const float* Wv1 = (const float*)d_in[12];
    const float* bv1 = (const float*)d_in[13];
    const float* Wv2 = (const float*)d_in[14];
    const float* bv2 = (const float*)d_in[15];
    const float* Wn1 = (const float*)d_in[16];
    const float* bn1 = (const float*)d_in[17];
    const float* Wn2 = (const float*)d_in[18];
    const float* bn2 = (const float*)d_in[19];

    char* ws = (char*)d_ws;
    float* m_acc = (float*)ws;                                  // [NN][128] f32 sigma-packed
    float* c_sum = (float*)(ws + 25600000);                     // [NN][3] f32
    int* deg    = (int*)(ws + 26200000);                        // [NN]
    int* cursor = (int*)(ws + 26400000);                        // [NN]
    int* gcount = (int*)(ws + 26600000);                        // [1] scan base counter
    // --- single memset covers everything above: [0, 26600064)
    unsigned short* hb   = (unsigned short*)(ws + 26600064);    // [NN][128] bf16
    unsigned short* Wt1  = (unsigned short*)(ws + 39400064);
    unsigned short* Wt2  = (unsigned short*)(ws + 39465600);
    unsigned short* Wt3  = (unsigned short*)(ws + 39498368);
    unsigned short* Wv1t = (unsigned short*)(ws + 39531136);
    unsigned short* Wn1t = (unsigned short*)(ws + 39563904);
    unsigned short* Wn2t = (unsigned short*)(ws + 39629440);
    int* rowptr = (int*)(ws + 39662208);                        // [NN]
    int* csr_r  = (int*)(ws + 39862272);                        // [NE]
    int* csr_c  = (int*)(ws + 41862272);                        // [NE]

    hipMemsetAsync(ws, 0, 26600064, stream);

    setup_all<<<6762 + 1954, 256, 0, stream>>>(
        h, hb, We1, We2, Wc1, Wv1, Wn1, Wn2,
        Wt1, Wt2, Wt3, Wv1t, Wn1t, Wn2t, eidx, deg);

    scan_fused<<<196, 256, 0, stream>>>(deg, gcount, rowptr);
    csr_fill<<<1954, 256, 0, stream>>>(eidx, rowptr, cursor, csr_r, csr_c);

    egcl_edge<<<NEB, BLK, 0, stream>>>(
        coord, csr_r, csr_c, hb, Wt1, Wt2, Wt3,
        We1, be1, be2, bc1, Wc2, bc2, m_acc, c_sum);

    float* out_h = (float*)d_out;
    float* out_c = out_h + (size_t)NN * 128;
    egcl_node<<<(NN + 63) / 64, BLK, 0, stream>>>(
        hb, coord, vel, Wv1t, bv1, Wv2, bv2, Wn1t, bn1, Wn2t, bn2,
        m_acc, c_sum, out_h, out_c);
}

// Round 9
// 494.220 us; speedup vs baseline: 1.5920x; 1.5920x over previous
//
#include <hip/hip_runtime.h>
#include <stdint.h>

#define NN 50000
#define NE 500000
#define BLK 256
#define NEB ((NE + 127) / 128)
#define SST 136   // LDS row stride in shorts (272 B -> 2-way banks on b128 reads)

#define BARRIER() asm volatile("s_waitcnt lgkmcnt(0)\n\ts_barrier" ::: "memory")

typedef __attribute__((ext_vector_type(8))) short bf16x8;
typedef __attribute__((ext_vector_type(4))) float f32x4;

__device__ __forceinline__ float fastrcp(float x) {
    float r; asm("v_rcp_f32 %0, %1" : "=v"(r) : "v"(x)); return r;
}
__device__ __forceinline__ float silu(float x) {          // fast: mul+exp+add+rcp+mul
    return x * fastrcp(1.0f + __expf(-x));
}
__device__ __forceinline__ float bf2f(unsigned short s) {
    union { unsigned int u; float f; } v; v.u = ((unsigned int)s) << 16; return v.f;
}
__device__ __forceinline__ float ulo(unsigned int u) { union { unsigned int x; float f; } v; v.x = u << 16;         return v.f; }
__device__ __forceinline__ float uhi(unsigned int u) { union { unsigned int x; float f; } v; v.x = u & 0xffff0000u; return v.f; }
__device__ __forceinline__ unsigned short f2bf(float f) {   // RNE (setup only)
    union { float f; unsigned int u; } v; v.f = f;
    return (unsigned short)((v.u + 0x7fffu + ((v.u >> 16) & 1u)) >> 16);
}
__device__ __forceinline__ unsigned int pack2(float a, float b) {   // RNE pair (setup only)
    return (unsigned int)f2bf(a) | ((unsigned int)f2bf(b) << 16);
}
__device__ __forceinline__ unsigned int pack2t(float a, float b) {  // truncating pair, 1 v_perm
    return __builtin_amdgcn_perm(__float_as_uint(b), __float_as_uint(a), 0x07060302u);
}
__device__ __forceinline__ bf16x8 packf8t(const float* p) {         // 8 fp32 -> bf16x8, 4 perms
    float4 f0 = *(const float4*)p; float4 f1 = *(const float4*)(p + 4);
    union { bf16x8 v; unsigned int u[4]; } o;
    o.u[0] = pack2t(f0.x, f0.y); o.u[1] = pack2t(f0.z, f0.w);
    o.u[2] = pack2t(f1.x, f1.y); o.u[3] = pack2t(f1.z, f1.w);
    return o.v;
}

// ---------------- fused setup: prep_h | prep_w | csr_count by block range ----------------
__global__ void setup_all(const float* __restrict__ h, unsigned short* __restrict__ hb,
                          const float* __restrict__ We1, const float* __restrict__ We2,
                          const float* __restrict__ Wc1, const float* __restrict__ Wv1,
                          const float* __restrict__ Wn1, const float* __restrict__ Wn2,
                          unsigned short* __restrict__ Wt1, unsigned short* __restrict__ Wt2,
                          unsigned short* __restrict__ Wt3, unsigned short* __restrict__ Wv1t,
                          unsigned short* __restrict__ Wn1t, unsigned short* __restrict__ Wn2t,
                          const int* __restrict__ eidx, int* __restrict__ deg) {
    int bid = blockIdx.x;
    if (bid < 6250) {                       // prep_h: fp32 -> bf16 (RNE)
        int i = bid * 256 + threadIdx.x;
        if (i < NN * 128 / 4) {
            float4 v = ((const float4*)h)[i];
            uint2 o; o.x = pack2(v.x, v.y); o.y = pack2(v.z, v.w);
            ((uint2*)hb)[i] = o;
        }
    } else if (bid < 6762) {                // prep_w: B^T layouts (sigma: orig_k = (ks%8)*16+ks/8)
        int i = (bid - 6250) * 256 + threadIdx.x;
        if (i < 32768) {                                    // Wt1 [128][256] natural
            int j = i >> 8, k = i & 255;
            Wt1[i] = f2bf(We1[k * 128 + j]);
        } else if (i < 49152) {                             // Wt2 sigma
            int t = i - 32768; int j = t >> 7, ks = t & 127;
            int k0 = (ks & 7) * 16 + (ks >> 3);
            Wt2[t] = f2bf(We2[k0 * 128 + j]);
        } else if (i < 65536) {                             // Wt3 sigma
            int t = i - 49152; int j = t >> 7, ks = t & 127;
            int k0 = (ks & 7) * 16 + (ks >> 3);
            Wt3[t] = f2bf(Wc1[k0 * 128 + j]);
        } else if (i < 81920) {                             // Wv1t natural
            int t = i - 65536; int j = t >> 7, k = t & 127;
            Wv1t[t] = f2bf(Wv1[k * 128 + j]);
        } else if (i < 114688) {                            // Wn1t: h natural, m sigma
            int t = i - 81920; int j = t >> 8, k = t & 255;
            int ksrc;
            if (k < 128) ksrc = k;
            else { int ks = k - 128; ksrc = 128 + (ks & 7) * 16 + (ks >> 3); }
            Wn1t[t] = f2bf(Wn1[ksrc * 128 + j]);
        } else if (i < 131072) {                            // Wn2t sigma
            int t = i - 114688; int j = t >> 7, ks = t & 127;
            int k0 = (ks & 7) * 16 + (ks >> 3);
            Wn2t[t] = f2bf(Wn2[k0 * 128 + j]);
        }
    } else {                                // csr_count
        int e = (bid - 6762) * 256 + threadIdx.x;
        if (e < NE) atomicAdd(&deg[eidx[e]], 1);
    }
}

// ---------------- single-kernel scan (order-free base via atomic) ----------------
__global__ void scan_fused(const int* __restrict__ deg, int* __restrict__ gcount,
                           int* __restrict__ rowptr) {
    __shared__ int s[256];
    __shared__ int base;
    int t = threadIdx.x, idx = blockIdx.x * 256 + t;
    int v = (idx < NN) ? deg[idx] : 0;
    s[t] = v;
    __syncthreads();
    for (int off = 1; off < 256; off <<= 1) {
        int x = (t >= off) ? s[t - off] : 0;
        __syncthreads();
        s[t] += x;
        __syncthreads();
    }
    if (t == 255) base = atomicAdd(gcount, s[255]);
    __syncthreads();
    if (idx < NN) rowptr[idx] = base + s[t] - v;
}

__global__ void csr_fill(const int* __restrict__ eidx, const int* __restrict__ rowptr,
                         int* __restrict__ cursor,
                         int* __restrict__ csr_r, int* __restrict__ csr_c) {
    int e = blockIdx.x * 256 + threadIdx.x;
    if (e < NE) {
        int r = eidx[e], c = eidx[NE + e];
        int slot = rowptr[r] + atomicAdd(&cursor[r], 1);
        csr_r[slot] = r; csr_c[slot] = c;
    }
}

// ---------------- LDS staging helpers ----------------
__device__ __forceinline__ void stage256(const unsigned short* __restrict__ W, int halfk,
                                         unsigned short* sW, int tid) {
#pragma unroll
    for (int t = 0; t < 8; ++t) {
        int idx = tid + t * 256; int j = idx >> 4, g = idx & 15;
        *(uint4*)(sW + j * SST + g * 8) = *(const uint4*)(W + (size_t)j * 256 + halfk * 128 + g * 8);
    }
}
__device__ __forceinline__ void stage128(const unsigned short* __restrict__ W,
                                         unsigned short* sW, int tid) {
#pragma unroll
    for (int t = 0; t < 8; ++t) {
        int idx = tid + t * 256; int j = idx >> 4, g = idx & 15;
        *(uint4*)(sW + j * SST + g * 8) = *(const uint4*)(W + (size_t)j * 128 + g * 8);
    }
}
__device__ __forceinline__ void mfma4(const bf16x8 a[2][4], const unsigned short* sW,
                                      int l16, int q, f32x4 acc[2][8]) {
#pragma unroll
    for (int kc = 0; kc < 4; ++kc)
#pragma unroll
        for (int ct = 0; ct < 8; ++ct) {
            bf16x8 b = *(const bf16x8*)(sW + (ct * 16 + l16) * SST + kc * 32 + q * 8);
            acc[0][ct] = __builtin_amdgcn_mfma_f32_16x16x32_bf16(a[0][kc], b, acc[0][ct], 0, 0, 0);
            acc[1][ct] = __builtin_amdgcn_mfma_f32_16x16x32_bf16(a[1][kc], b, acc[1][ct], 0, 0, 0);
        }
}

// ---------------- edge kernel: R6 structure (LDS-staged B), fast epilogues ----------------
__global__ __launch_bounds__(BLK, 2) void egcl_edge(
    const float* __restrict__ coord,
    const int* __restrict__ csr_r, const int* __restrict__ csr_c,
    const unsigned short* __restrict__ hb,
    const unsigned short* __restrict__ Wt1,
    const unsigned short* __restrict__ Wt2,
    const unsigned short* __restrict__ Wt3,
    const float* __restrict__ We1,
    const float* __restrict__ be1, const float* __restrict__ be2,
    const float* __restrict__ bc1,
    const float* __restrict__ Wc2, const float* __restrict__ bc2,
    float* __restrict__ m_acc, float* __restrict__ c_sum)
{
    __shared__ __align__(16) unsigned short sAb[128 * SST];
    __shared__ __align__(16) unsigned short sW[128 * SST];
    __shared__ float sRad[128], sDif[128][3];
    __shared__ int sRr[128], sRc[128], sSeg[128];
    __shared__ float sBe1[128], sBe2[128], sBc1[128], sWlast[128], sWc2f[128];

    const int tid = threadIdx.x;
    const int wv = tid >> 6, lane = tid & 63, q = lane >> 4, l16 = lane & 15;
    const int e0 = blockIdx.x * 128;

    if (tid < 128) {
        sBe1[tid] = be1[tid]; sBe2[tid] = be2[tid]; sBc1[tid] = bc1[tid];
        sWlast[tid] = We1[256 * 128 + tid]; sWc2f[tid] = Wc2[tid];
        int s = e0 + tid; int sc = (s < NE) ? s : (NE - 1);
        int r = csr_r[sc], c = csr_c[sc];
        sRr[tid] = r; sRc[tid] = c;
        sSeg[tid] = (s < NE) ? r : -1;
        float dx = coord[r * 3 + 0] - coord[c * 3 + 0];
        float dy = coord[r * 3 + 1] - coord[c * 3 + 1];
        float dz = coord[r * 3 + 2] - coord[c * 3 + 2];
        float rad = fmaf(dx, dx, fmaf(dy, dy, dz * dz));
        float inv = 1.0f / (sqrtf(rad) + 1e-8f);
        sRad[tid] = rad;
        sDif[tid][0] = dx * inv; sDif[tid][1] = dy * inv; sDif[tid][2] = dz * inv;
    }
    stage256(Wt1, 0, sW, tid);
    const float bc2v = bc2[0];
    BARRIER();   // A: geometry + Wt1a visible

    f32x4 acc[2][8];
#pragma unroll
    for (int si = 0; si < 2; ++si)
#pragma unroll
        for (int ct = 0; ct < 8; ++ct) acc[si][ct] = (f32x4){0.f, 0.f, 0.f, 0.f};

    // ---- e1 half 0: A = h[r]
    {
        bf16x8 a[2][4];
#pragma unroll
        for (int si = 0; si < 2; ++si) {
            int node = sRr[(wv * 2 + si) * 16 + l16];
#pragma unroll
            for (int kc = 0; kc < 4; ++kc)
                a[si][kc] = *(const bf16x8*)(hb + (size_t)node * 128 + kc * 32 + q * 8);
        }
        mfma4(a, sW, l16, q, acc);
    }
    BARRIER();   // B: Wt1a reads done
    stage256(Wt1, 1, sW, tid);
    BARRIER();   // C: Wt1b visible
    // ---- e1 half 1: A = h[c]
    {
        bf16x8 a[2][4];
#pragma unroll
        for (int si = 0; si < 2; ++si) {
            int node = sRc[(wv * 2 + si) * 16 + l16];
#pragma unroll
            for (int kc = 0; kc < 4; ++kc)
                a[si][kc] = *(const bf16x8*)(hb + (size_t)node * 128 + kc * 32 + q * 8);
        }
        mfma4(a, sW, l16, q, acc);
    }
    BARRIER();   // D: Wt1b reads done

    // e1 epilogue: t1 = silu(acc + rad*Wlast + be1) -> sigma pack into sAb; stage Wt2
#pragma unroll
    for (int si = 0; si < 2; ++si)
#pragma unroll
        for (int r = 0; r < 4; ++r) {
            int row = (wv * 2 + si) * 16 + q * 4 + r;
            float rad = sRad[row];
            float v[8];
#pragma unroll
            for (int ct = 0; ct < 8; ++ct) {
                int col = ct * 16 + l16;
                v[ct] = silu(acc[si][ct][r] + rad * sWlast[col] + sBe1[col]);
            }
            uint4 pk = make_uint4(pack2t(v[0], v[1]), pack2t(v[2], v[3]),
                                  pack2t(v[4], v[5]), pack2t(v[6], v[7]));
            *(uint4*)(sAb + row * SST + l16 * 8) = pk;
        }
    stage128(Wt2, sW, tid);
    BARRIER();   // E: t1 + Wt2 visible

    // ---- e2: m = silu(t1 @ We2 + be2)
#pragma unroll
    for (int si = 0; si < 2; ++si)
#pragma unroll
        for (int ct = 0; ct < 8; ++ct) acc[si][ct] = (f32x4){0.f, 0.f, 0.f, 0.f};
    {
        bf16x8 a[2][4];
#pragma unroll
        for (int si = 0; si < 2; ++si) {
            int row = (wv * 2 + si) * 16 + l16;
#pragma unroll
            for (int kc = 0; kc < 4; ++kc)
                a[si][kc] = *(const bf16x8*)(sAb + row * SST + kc * 32 + q * 8);
        }
        mfma4(a, sW, l16, q, acc);
    }
    uint4 mu[2][4];
#pragma unroll
    for (int si = 0; si < 2; ++si)
#pragma unroll
        for (int r = 0; r < 4; ++r) {
            float v[8];
#pragma unroll
            for (int ct = 0; ct < 8; ++ct) v[ct] = silu(acc[si][ct][r] + sBe2[ct * 16 + l16]);
            mu[si][r] = make_uint4(pack2t(v[0], v[1]), pack2t(v[2], v[3]),
                                   pack2t(v[4], v[5]), pack2t(v[6], v[7]));
        }
    BARRIER();   // F: sAb t1-reads + Wt2 reads done
#pragma unroll
    for (int si = 0; si < 2; ++si)
#pragma unroll
        for (int r = 0; r < 4; ++r) {
            int row = (wv * 2 + si) * 16 + q * 4 + r;
            *(uint4*)(sAb + row * SST + l16 * 8) = mu[si][r];
        }
    stage128(Wt3, sW, tid);
    BARRIER();   // G: m + Wt3 visible

    // ---- c1
#pragma unroll
    for (int si = 0; si < 2; ++si)
#pragma unroll
        for (int ct = 0; ct < 8; ++ct) acc[si][ct] = (f32x4){0.f, 0.f, 0.f, 0.f};
    {
        bf16x8 a[2][4];
#pragma unroll
        for (int si = 0; si < 2; ++si) {
            int row = (wv * 2 + si) * 16 + l16;
#pragma unroll
            for (int kc = 0; kc < 4; ++kc)
                a[si][kc] = *(const bf16x8*)(sAb + row * SST + kc * 32 + q * 8);
        }
        mfma4(a, sW, l16, q, acc);
    }
    // c2: silu -> dot Wc2 -> 16-lane reduce -> c_sum atomics (1.5M total)
#pragma unroll
    for (int si = 0; si < 2; ++si) {
        float p[4];
#pragma unroll
        for (int r = 0; r < 4; ++r) {
            float s = 0.f;
#pragma unroll
            for (int ct = 0; ct < 8; ++ct) {
                int col = ct * 16 + l16;
                float t = silu(acc[si][ct][r] + sBc1[col]);
                s = fmaf(t, sWc2f[col], s);
            }
            p[r] = s;
        }
#pragma unroll
        for (int m = 1; m < 16; m <<= 1)
#pragma unroll
            for (int r = 0; r < 4; ++r) p[r] += __shfl_xor(p[r], m, 16);
        if (l16 == 0) {
#pragma unroll
            for (int r = 0; r < 4; ++r) {
                int row = (wv * 2 + si) * 16 + q * 4 + r;
                int rn = sSeg[row];
                if (rn >= 0) {
                    float w = p[r] + bc2v;
                    atomicAdd(&c_sum[(size_t)rn * 3 + 0], sDif[row][0] * w);
                    atomicAdd(&c_sum[(size_t)rn * 3 + 1], sDif[row][1] * w);
                    atomicAdd(&c_sum[(size_t)rn * 3 + 2], sDif[row][2] * w);
                }
            }
        }
    }

    // ---- segmented m reduction: 2 packed cols/thread over 32-row windows
    {
        int cp = (tid & 63) * 2;    // column pair
        int base = (tid >> 6) * 32; // window
        float run0 = 0.f, run1 = 0.f;
        int cur = sSeg[base];
        bool openL = true;
#pragma unroll 1
        for (int i = 0; i < 32; ++i) {
            int row = base + i;
            int rr = sSeg[row];
            if (rr != cur) {
                if (cur >= 0) {
                    float* dst = &m_acc[(size_t)cur * 128 + cp];
                    if (openL) { atomicAdd(dst, run0); atomicAdd(dst + 1, run1); }
                    else       { dst[0] = run0; dst[1] = run1; }   // window-interior: exclusive
                }
                run0 = run1 = 0.f; cur = rr; openL = false;
            }
            unsigned int u = *(const unsigned int*)(sAb + row * SST + cp);
            run0 += ulo(u); run1 += uhi(u);
        }
        if (cur >= 0) {
            float* dst = &m_acc[(size_t)cur * 128 + cp];
            atomicAdd(dst, run0); atomicAdd(dst + 1, run1);
        }
    }
}

// ---------------- node kernel: 64 nodes/block ----------------
__global__ __launch_bounds__(BLK, 3) void egcl_node(
    const unsigned short* __restrict__ hb,
    const float* __restrict__ coord,
    const float* __restrict__ vel,
    const unsigned short* __restrict__ Wv1t, const float* __restrict__ bv1,
    const float* __restrict__ Wv2, const float* __restrict__ bv2,
    const unsigned short* __restrict__ Wn1t, const float* __restrict__ bn1,
    const unsigned short* __restrict__ Wn2t, const float* __restrict__ bn2,
    const float* __restrict__ m_acc, const float* __restrict__ c_sum,
    float* __restrict__ out_h, float* __restrict__ out_c)
{
    __shared__ __align__(16) unsigned short sAb[64 * SST];
    __shared__ float sBv1[128], sWv2f[128], sBn1[128], sBn2[128];

    const int tid = threadIdx.x;
    const int wv = tid >> 6, lane = tid & 63, q = lane >> 4, l16 = lane & 15;
    const int n0 = blockIdx.x * 64;
    int nval = NN - n0; if (nval > 64) nval = 64;

    if (tid < 128) {
        sBv1[tid] = bv1[tid]; sWv2f[tid] = Wv2[tid];
        sBn1[tid] = bn1[tid]; sBn2[tid] = bn2[tid];
    }
    const float bv2v = bv2[0];

    bf16x8 ah[4], am[4];
    {
        int row = wv * 16 + l16;
        int nn = n0 + row; if (nn >= NN) nn = NN - 1;
#pragma unroll
        for (int kc = 0; kc < 4; ++kc) {
            ah[kc] = *(const bf16x8*)(hb + (size_t)nn * 128 + kc * 32 + q * 8);
            am[kc] = packf8t(m_acc + (size_t)nn * 128 + kc * 32 + q * 8);
        }
    }

    BARRIER();   // biases visible

    f32x4 acc[8];
    // ---- vel MLP
#pragma unroll
    for (int ct = 0; ct < 8; ++ct) acc[ct] = (f32x4){0.f, 0.f, 0.f, 0.f};
#pragma unroll
    for (int kc = 0; kc < 4; ++kc)
#pragma unroll
        for (int ct = 0; ct < 8; ++ct) {
            bf16x8 b = *(const bf16x8*)(Wv1t + (size_t)(ct * 16 + l16) * 128 + kc * 32 + q * 8);
            acc[ct] = __builtin_amdgcn_mfma_f32_16x16x32_bf16(ah[kc], b, acc[ct], 0, 0, 0);
        }
    {
        float p[4];
#pragma unroll
        for (int r = 0; r < 4; ++r) {
            float s = 0.f;
#pragma unroll
            for (int ct = 0; ct < 8; ++ct) {
                int col = ct * 16 + l16;
                float t = silu(acc[ct][r] + sBv1[col]);
                s = fmaf(t, sWv2f[col], s);
            }
            p[r] = s;
        }
#pragma unroll
        for (int m = 1; m < 16; m <<= 1)
#pragma unroll
            for (int r = 0; r < 4; ++r) p[r] += __shfl_xor(p[r], m, 16);
        if (l16 == 0) {
#pragma unroll
            for (int r = 0; r < 4; ++r) {
                int row = wv * 16 + q * 4 + r;
                int n = n0 + row;
                if (row < nval) {
                    float vw = p[r] + bv2v;
#pragma unroll
                    for (int d = 0; d < 3; ++d) {
                        float cv = coord[(size_t)n * 3 + d] + c_sum[(size_t)n * 3 + d]
                                 + vel[(size_t)n * 3 + d] * vw;
                        out_c[(size_t)n * 3 + d] = cv;
                    }
                }
            }
        }
    }

    // ---- n1: K=256 on [h | m_i]
#pragma unroll
    for (int ct = 0; ct < 8; ++ct) acc[ct] = (f32x4){0.f, 0.f, 0.f, 0.f};
#pragma unroll
    for (int kc = 0; kc < 8; ++kc)
#pragma unroll
        for (int ct = 0; ct < 8; ++ct) {
            bf16x8 b = *(const bf16x8*)(Wn1t + (size_t)(ct * 16 + l16) * 256 + kc * 32 + q * 8);
            bf16x8 a = (kc < 4) ? ah[kc & 3] : am[kc & 3];
            acc[ct] = __builtin_amdgcn_mfma_f32_16x16x32_bf16(a, b, acc[ct], 0, 0, 0);
        }
#pragma unroll
    for (int r = 0; r < 4; ++r) {
        int row = wv * 16 + q * 4 + r;
        float v[8];
#pragma unroll
        for (int ct = 0; ct < 8; ++ct) v[ct] = silu(acc[ct][r] + sBn1[ct * 16 + l16]);
        uint4 pk = make_uint4(pack2t(v[0], v[1]), pack2t(v[2], v[3]),
                              pack2t(v[4], v[5]), pack2t(v[6], v[7]));
        *(uint4*)(sAb + row * SST + l16 * 8) = pk;
    }

    BARRIER();   // t1 visible

    // ---- n2
#pragma unroll
    for (int ct = 0; ct < 8; ++ct) acc[ct] = (f32x4){0.f, 0.f, 0.f, 0.f};
    {
        bf16x8 a[4];
        int row = wv * 16 + l16;
#pragma unroll
        for (int kc = 0; kc < 4; ++kc)
            a[kc] = *(const bf16x8*)(sAb + row * SST + kc * 32 + q * 8);
#pragma unroll
        for (int kc = 0; kc < 4; ++kc)
#pragma unroll
            for (int ct = 0; ct < 8; ++ct) {
                bf16x8 b = *(const bf16x8*)(Wn2t + (size_t)(ct * 16 + l16) * 128 + kc * 32 + q * 8);
                acc[ct] = __builtin_amdgcn_mfma_f32_16x16x32_bf16(a[kc], b, acc[ct], 0, 0, 0);
            }
    }
#pragma unroll
    for (int r = 0; r < 4; ++r) {
        int row = wv * 16 + q * 4 + r;
        if (row < nval) {
            float* orow = out_h + (size_t)(n0 + row) * 128;
#pragma unroll
            for (int ct = 0; ct < 8; ++ct)
                orow[ct * 16 + l16] = acc[ct][r] + sBn2[ct * 16 + l16];
        }
    }
}

extern "C" void kernel_launch(void* const* d_in, const int* in_sizes, int n_in,
                              void* d_out, int out_size, void* d_ws, size_t ws_size,
                              hipStream_t stream) {
    const float* h     = (const float*)d_in[0];
    const float* coord = (const float*)d_in[1];
    const float* vel   = (const float*)d_in[2];
    const int*   eidx  = (const int*)d_in[3];
    const float* We1 = (const float*)d_in[4];
    const float* be1 = (const float*)d_in[5];
    const float* We2 = (const float*)d_in[6];
    const float* be2 = (const float*)d_in[7];
    const float* Wc1 = (const float*)d_in[8];
    const float* bc1 = (const float*)d_in[9];
    const float* Wc2 = (const float*)d_in[10];
    const float* bc2 = (const float*)d_in[11];
    const float* Wv1 = (const float*)d_in[12];
    const float* bv1 = (const float*)d_in[13];
    const float* Wv2 = (const float*)d_in[14];
    const float* bv2 = (const float*)d_in[15];
    const float* Wn1 = (const float*)d_in[16];
    const float* bn1 = (const float*)d_in[17];
    const float* Wn2 = (const float*)d_in[18];
    const float* bn2 = (const float*)d_in[19];

    char* ws = (char*)d_ws;
    float* m_acc = (float*)ws;                                  // [NN][128] f32 sigma-packed
    float* c_sum = (float*)(ws + 25600000);                     // [NN][3] f32
    int* deg    = (int*)(ws + 26200000);                        // [NN]
    int* cursor = (int*)(ws + 26400000);                        // [NN]
    int* gcount = (int*)(ws + 26600000);                        // [1]
    // --- single memset covers everything above: [0, 26600064)
    unsigned short* hb   = (unsigned short*)(ws + 26600064);    // [NN][128] bf16
    unsigned short* Wt1  = (unsigned short*)(ws + 39400064);
    unsigned short* Wt2  = (unsigned short*)(ws + 39465600);
    unsigned short* Wt3  = (unsigned short*)(ws + 39498368);
    unsigned short* Wv1t = (unsigned short*)(ws + 39531136);
    unsigned short* Wn1t = (unsigned short*)(ws + 39563904);
    unsigned short* Wn2t = (unsigned short*)(ws + 39629440);
    int* rowptr = (int*)(ws + 39662208);                        // [NN]
    int* csr_r  = (int*)(ws + 39862272);                        // [NE]
    int* csr_c  = (int*)(ws + 41862272);                        // [NE]

    hipMemsetAsync(ws, 0, 26600064, stream);

    setup_all<<<6762 + 1954, 256, 0, stream>>>(
        h, hb, We1, We2, Wc1, Wv1, Wn1, Wn2,
        Wt1, Wt2, Wt3, Wv1t, Wn1t, Wn2t, eidx, deg);

    scan_fused<<<196, 256, 0, stream>>>(deg, gcount, rowptr);
    csr_fill<<<1954, 256, 0, stream>>>(eidx, rowptr, cursor, csr_r, csr_c);

    egcl_edge<<<NEB, BLK, 0, stream>>>(
        coord, csr_r, csr_c, hb, Wt1, Wt2, Wt3,
        We1, be1, be2, bc1, Wc2, bc2, m_acc, c_sum);

    float* out_h = (float*)d_out;
    float* out_c = out_h + (size_t)NN * 128;
    egcl_node<<<(NN + 63) / 64, BLK, 0, stream>>>(
        hb, coord, vel, Wv1t, bv1, Wv2, bv2, Wn1t, bn1, Wn2t, bn2,
        m_acc, c_sum, out_h, out_c);
}